// Round 10
// baseline (190.020 us; speedup 1.0000x reference)
//
#include <hip/hip_runtime.h>
#include <hip/hip_bf16.h>
#include <hip/hip_fp16.h>

typedef __attribute__((ext_vector_type(8))) short bf16x8;   // 8 bf16 = 4 VGPRs
typedef __attribute__((ext_vector_type(4))) float f32x4;
typedef unsigned short u16;
typedef unsigned int uint;

#define Bb 2
#define Tt 2048
#define Dd 1024
#define Hh 16

#define EXP2F(x) __builtin_amdgcn_exp2f(x)

__device__ inline u16 f2bf(float f) {
    union { float f; uint u; } v; v.f = f;
    uint r = v.u + 0x7fffu + ((v.u >> 16) & 1u);   // RNE
    return (u16)(r >> 16);
}
__device__ inline uint fbits(float f) { union { float f; uint u; } v; v.f = f; return v.u; }
__device__ inline u16 f2h(float f) { return __half_as_ushort(__float2half(f)); }
__device__ inline float h2f(u16 u) { return __half2float(__ushort_as_half(u)); }

// async global->LDS, 16B per lane; dest wave-uniform base + lane*16.
__device__ inline void glds16(const u16* g, u16* l) {
    __builtin_amdgcn_global_load_lds(
        (const __attribute__((address_space(1))) void*)g,
        (__attribute__((address_space(3))) void*)l,
        16, 0, 0);
}

// ---------------------------------------------------------------------------
// fp32 -> bf16 elementwise (8 elems/thread)
// ---------------------------------------------------------------------------
__global__ __launch_bounds__(256) void cvt_bf16(
    const float* __restrict__ in, u16* __restrict__ out)
{
    const size_t i = ((size_t)blockIdx.x * 256 + threadIdx.x) * 8;
    const float4 a = *(const float4*)&in[i];
    const float4 b = *(const float4*)&in[i + 4];
    uint4 o;
    o.x = (uint)f2bf(a.x) | ((uint)f2bf(a.y) << 16);
    o.y = (uint)f2bf(a.z) | ((uint)f2bf(a.w) << 16);
    o.z = (uint)f2bf(b.x) | ((uint)f2bf(b.y) << 16);
    o.w = (uint)f2bf(b.z) | ((uint)f2bf(b.w) << 16);
    *(uint4*)&out[i] = o;
}

// ---------------------------------------------------------------------------
// W[K][N] fp32 -> Wt[N][K] bf16, 64x64 LDS tile
// ---------------------------------------------------------------------------
__global__ __launch_bounds__(256) void transpose_cvt(
    const float* __restrict__ W, u16* __restrict__ Wt, int K, int N)
{
    __shared__ float tile[64][65];
    const int k0 = blockIdx.y * 64, n0 = blockIdx.x * 64;
    const int tid = threadIdx.x;
    const int tr = tid >> 4;
    const int tc = (tid & 15) * 4;

    #pragma unroll
    for (int i = 0; i < 4; ++i) {
        const float4 v = *(const float4*)&W[(size_t)(k0 + tr + i * 16) * N + n0 + tc];
        tile[tr + i * 16][tc + 0] = v.x;
        tile[tr + i * 16][tc + 1] = v.y;
        tile[tr + i * 16][tc + 2] = v.z;
        tile[tr + i * 16][tc + 3] = v.w;
    }
    __syncthreads();
    #pragma unroll
    for (int i = 0; i < 4; ++i) {
        ushort4 o;
        o.x = f2bf(tile[tc + 0][tr + i * 16]);
        o.y = f2bf(tile[tc + 1][tr + i * 16]);
        o.z = f2bf(tile[tc + 2][tr + i * 16]);
        o.w = f2bf(tile[tc + 3][tr + i * 16]);
        *(ushort4*)&Wt[(size_t)(n0 + tr + i * 16) * K + k0 + tc] = o;
    }
}

// ---------------------------------------------------------------------------
// C = A @ Bt^T + bias, bf16 MFMA. 3-stage software pipeline with RAW barriers:
// raw s_barrier (no implicit vmcnt(0) drain) + explicit s_waitcnt vmcnt(4)
// waits only for THIS iter's 4 glds while the next iter's 4 stay in flight.
// Each load gets ~2 compute phases of latency cover (vs 1 with __syncthreads).
// Buffer rotation: iter it reads buf it%3, issues glds(it+2) into (it+2)%3
// AFTER the barrier -> last readers of that buf (iter it-1) are provably done.
// MODE 0: fp32 out, row-major stride N (gemm2).
// MODE 1: qkv proj: cols <2048 -> bf16 qkvb stride 2048 (Q,K);
//         cols >=2048 -> V scattered transposed into vg[b][h][d][T].
// ---------------------------------------------------------------------------
template <int MODE>
__global__ __launch_bounds__(256) void gemm_bt(
    const u16* __restrict__ A, const u16* __restrict__ Bt,
    const float* __restrict__ bias, void* __restrict__ C,
    u16* __restrict__ vg, int M, int N, int K)
{
    __shared__ u16 As[3][128 * 32];
    __shared__ u16 Bs[3][128 * 32];

    const int tid  = threadIdx.x;
    const int lane = tid & 63;
    const int w    = tid >> 6;
    const int wm   = w >> 1, wn = w & 1;
    const int quad = lane >> 4;
    const int m16  = lane & 15;
    const int row0 = blockIdx.y * 128;
    const int col0 = blockIdx.x * 128;

    f32x4 acc[4][4];
    #pragma unroll
    for (int i = 0; i < 4; ++i)
        #pragma unroll
        for (int j = 0; j < 4; ++j) acc[i][j] = (f32x4){0.f, 0.f, 0.f, 0.f};

    const int sr  = tid >> 2, sqs = tid & 3;
    const int sq  = sqs ^ ((sr >> 1) & 3);
    const int ldsw = w * 512;
    const int slot = quad ^ ((m16 >> 1) & 3);

    const int nIter = K >> 5;
    const u16* arow0 = &A [(size_t)(row0 + sr) * K + sq * 8];
    const u16* arow1 = &A [(size_t)(row0 + sr + 64) * K + sq * 8];
    const u16* brow0 = &Bt[(size_t)(col0 + sr) * K + sq * 8];
    const u16* brow1 = &Bt[(size_t)(col0 + sr + 64) * K + sq * 8];

    // prologue: stage iters 0,1 into bufs 0,1 (8 loads in flight)
    glds16(arow0,      &As[0][ldsw]);
    glds16(arow1,      &As[0][2048 + ldsw]);
    glds16(brow0,      &Bs[0][ldsw]);
    glds16(brow1,      &Bs[0][2048 + ldsw]);
    glds16(arow0 + 32, &As[1][ldsw]);
    glds16(arow1 + 32, &As[1][2048 + ldsw]);
    glds16(brow0 + 32, &Bs[1][ldsw]);
    glds16(brow1 + 32, &Bs[1][2048 + ldsw]);

    int cb = 0, pb = 2;   // current buf, prefetch buf (rotating mod 3)
    for (int it = 0; it < nIter; ++it) {
        // wait for THIS iter's loads only; keep next iter's 4 in flight
        if (it + 1 < nIter)
            asm volatile("s_waitcnt vmcnt(4)" ::: "memory");
        else
            asm volatile("s_waitcnt vmcnt(0)" ::: "memory");
        asm volatile("s_barrier" ::: "memory");

        if (it + 2 < nIter) {   // prefetch 2 ahead into rotated buffer
            const int ko = (it + 2) << 5;
            glds16(arow0 + ko, &As[pb][ldsw]);
            glds16(arow1 + ko, &As[pb][2048 + ldsw]);
            glds16(brow0 + ko, &Bs[pb][ldsw]);
            glds16(brow1 + ko, &Bs[pb][2048 + ldsw]);
        }

        bf16x8 af[4], bfr[4];
        #pragma unroll
        for (int mt = 0; mt < 4; ++mt)
            af[mt] = *(const bf16x8*)&As[cb][(wm * 64 + mt * 16 + m16) * 32 + slot * 8];
        #pragma unroll
        for (int nt = 0; nt < 4; ++nt)
            bfr[nt] = *(const bf16x8*)&Bs[cb][(wn * 64 + nt * 16 + m16) * 32 + slot * 8];
        #pragma unroll
        for (int mt = 0; mt < 4; ++mt)
            #pragma unroll
            for (int nt = 0; nt < 4; ++nt)
                acc[mt][nt] = __builtin_amdgcn_mfma_f32_16x16x32_bf16(
                    af[mt], bfr[nt], acc[mt][nt], 0, 0, 0);

        cb = (cb == 2) ? 0 : cb + 1;
        pb = (pb == 2) ? 0 : pb + 1;
    }

    #pragma unroll
    for (int mt = 0; mt < 4; ++mt) {
        #pragma unroll
        for (int nt = 0; nt < 4; ++nt) {
            const int row = row0 + wm * 64 + mt * 16 + quad * 4;
            const int col = col0 + wn * 64 + nt * 16 + m16;
            const float bv = bias[col];
            #pragma unroll
            for (int r = 0; r < 4; ++r) {
                const float v = acc[mt][nt][r] + bv;
                if (MODE == 0) {
                    ((float*)C)[(size_t)(row + r) * N + col] = v;
                } else {
                    if (col0 < 2048) {   // Q,K region (block never straddles)
                        ((u16*)C)[(size_t)(row + r) * 2048 + col] = f2bf(v);
                    } else {             // V: write transposed into vg[b][h][d][T]
                        const int hcol = col - 2048;
                        const int hh = hcol >> 6, dd = hcol & 63;
                        const int bb = (row + r) >> 11, tt = (row + r) & 2047;
                        vg[((size_t)(bb * Hh + hh) * 64 + dd) * Tt + tt] = f2bf(v);
                    }
                }
            }
        }
    }
}

// ---------------------------------------------------------------------------
// Flash causal attention v6: split-K(2) + fixed-offset softmax. (unchanged R8)
// ---------------------------------------------------------------------------
__global__ __launch_bounds__(256, 4) void attn_split(
    const u16* __restrict__ qkvb, const u16* __restrict__ vglob,
    u16* __restrict__ wsO, float* __restrict__ wsL)
{
    const int hb  = blockIdx.x;
    const int h   = hb & 15, b = hb >> 4;
    const int qt  = 15 - (blockIdx.y >> 1);   // heavy-first
    const int half = blockIdx.y & 1;
    const int tid = threadIdx.x;
    const int lane = tid & 63, w = tid >> 6;
    const int quad = lane >> 4, m16 = lane & 15;

    __shared__ u16 KV[2][64 * 64];       // [0]=K, [1]=Vt, 16 KB
    __shared__ u16 Pt[128 * 72];         // 18 KB

    const int q0 = qt * 128;
    const size_t qkbase = (size_t)(b * Tt) * 2048;
    const size_t vbase  = (size_t)((b * Hh + h) * 64) * Tt;

    const int sr8 = tid >> 3;                // 0..31
    const int sq8 = (tid & 7) ^ (sr8 & 7);
    const int ldsw = w * 512;
    const int slot = quad ^ (m16 & 7);       // ks=0 read slot; ks=1 -> ^4

    // Q^T B-frags, loop-invariant, from global:
    bf16x8 qb[2][2];
    #pragma unroll
    for (int nt = 0; nt < 2; ++nt)
        #pragma unroll
        for (int ks = 0; ks < 2; ++ks)
            qb[nt][ks] = *(const bf16x8*)&qkvb[
                qkbase + (size_t)(q0 + w * 32 + nt * 16 + m16) * 2048
                + h * 64 + ks * 32 + quad * 8];

    f32x4 o[4][2];
    #pragma unroll
    for (int ct = 0; ct < 4; ++ct)
        #pragma unroll
        for (int nt = 0; nt < 2; ++nt) o[ct][nt] = (f32x4){0.f, 0.f, 0.f, 0.f};
    float ls[2] = {0.f, 0.f};
    const float sc2 = 0.125f * 1.4426950408889634f;   // scale*log2(e)

    const int ntiles = 2 * qt + 2;
    for (int kt = half; kt < ntiles; kt += 2) {
        const int k0 = kt * 64;
        __syncthreads();   // all waves done with previous KV
        #pragma unroll
        for (int j = 0; j < 2; ++j) {
            const int row = j * 32 + sr8;
            glds16(&qkvb[qkbase + (size_t)(k0 + row) * 2048 + 1024 + h * 64 + sq8 * 8],
                   &KV[0][j * 2048 + ldsw]);
            glds16(&vglob[vbase + (size_t)row * Tt + k0 + sq8 * 8],
                   &KV[1][j * 2048 + ldsw]);
        }
        __syncthreads();   // vmcnt drain -> tiles visible

        if (k0 <= q0 + w * 32 + 31) {    // wave-uniform visibility
            const u16* Ks = KV[0];
            const u16* Vt = KV[1];

            // S^T = K · Q^T
            bf16x8 ak[4][2];
            #pragma unroll
            for (int mt = 0; mt < 4; ++mt) {
                const int ro = (mt * 16 + m16) * 64;
                ak[mt][0] = *(const bf16x8*)&Ks[ro + slot * 8];
                ak[mt][1] = *(const bf16x8*)&Ks[ro + (slot ^ 4) * 8];
            }
            f32x4 s[4][2];
            #pragma unroll
            for (int mt = 0; mt < 4; ++mt)
                #pragma unroll
                for (int nt = 0; nt < 2; ++nt) {
                    f32x4 a = (f32x4){0.f, 0.f, 0.f, 0.f};
                    a = __builtin_amdgcn_mfma_f32_16x16x32_bf16(ak[mt][0], qb[nt][0], a, 0, 0, 0);
                    a = __builtin_amdgcn_mfma_f32_16x16x32_bf16(ak[mt][1], qb[nt][1], a, 0, 0, 0);
                    s[mt][nt] = a;
                }

            // p = exp2(s*sc2 - 8), causal mask -> 0; accumulate l per-lane.
            const int qi0 = q0 + w * 32 + m16;
            const bool diag = (k0 + 63 > q0 + w * 32);
            #pragma unroll
            for (int mt = 0; mt < 4; ++mt)
                #pragma unroll
                for (int nt = 0; nt < 2; ++nt) {
                    float p[4];
                    const int kb = k0 + mt * 16 + quad * 4;
                    #pragma unroll
                    for (int r = 0; r < 4; ++r) {
                        float t = __builtin_fmaf(s[mt][nt][r], sc2, -8.0f);
                        if (diag) t = (kb + r <= qi0 + nt * 16) ? t : -1000.0f;
                        p[r] = EXP2F(t);
                    }
                    ls[nt] += (p[0] + p[1]) + (p[2] + p[3]);
                    uint2 pk;   // truncation-pack to bf16 pairs
                    pk.x = (fbits(p[0]) >> 16) | (fbits(p[1]) & 0xffff0000u);
                    pk.y = (fbits(p[2]) >> 16) | (fbits(p[3]) & 0xffff0000u);
                    *(uint2*)&Pt[(w * 32 + nt * 16 + m16) * 72 + mt * 16 + quad * 4] = pk;
                }

            // O^T += V^T · P^T  (same-wave Pt write->read)
            bf16x8 av[4][2], pb[2][2];
            #pragma unroll
            for (int ct = 0; ct < 4; ++ct) {
                const int ro = (ct * 16 + m16) * 64;
                av[ct][0] = *(const bf16x8*)&Vt[ro + slot * 8];
                av[ct][1] = *(const bf16x8*)&Vt[ro + (slot ^ 4) * 8];
            }
            #pragma unroll
            for (int nt = 0; nt < 2; ++nt)
                #pragma unroll
                for (int ks = 0; ks < 2; ++ks)
                    pb[nt][ks] = *(const bf16x8*)&Pt[(w * 32 + nt * 16 + m16) * 72 + ks * 32 + quad * 8];
            #pragma unroll
            for (int ct = 0; ct < 4; ++ct)
                #pragma unroll
                for (int nt = 0; nt < 2; ++nt) {
                    o[ct][nt] = __builtin_amdgcn_mfma_f32_16x16x32_bf16(av[ct][0], pb[nt][0], o[ct][nt], 0, 0, 0);
                    o[ct][nt] = __builtin_amdgcn_mfma_f32_16x16x32_bf16(av[ct][1], pb[nt][1], o[ct][nt], 0, 0, 0);
                }
        }
    }

    // epilogue: deferred l reduce (once), store fp16 O partial + fp32 l.
    #pragma unroll
    for (int nt = 0; nt < 2; ++nt) {
        ls[nt] += __shfl_xor(ls[nt], 16);
        ls[nt] += __shfl_xor(ls[nt], 32);
    }
    const int qrow = b * Tt + q0 + w * 32 + m16;
    if (quad == 0) {
        wsL[(half * Hh + h) * 4096 + qrow]      = ls[0];
        wsL[(half * Hh + h) * 4096 + qrow + 16] = ls[1];
    }
    #pragma unroll
    for (int ct = 0; ct < 4; ++ct)
        #pragma unroll
        for (int nt = 0; nt < 2; ++nt) {
            ushort4 pk;
            pk.x = f2h(o[ct][nt][0]);
            pk.y = f2h(o[ct][nt][1]);
            pk.z = f2h(o[ct][nt][2]);
            pk.w = f2h(o[ct][nt][3]);
            *(ushort4*)&wsO[((size_t)(half * 4096 + qrow + nt * 16)) * 1024
                            + h * 64 + ct * 16 + quad * 4] = pk;
        }
}

// ---------------------------------------------------------------------------
// combine: attb = bf16( (O0+O1) / (l0+l1) ), 8 elems/thread.
// ---------------------------------------------------------------------------
__global__ __launch_bounds__(256) void combine(
    const u16* __restrict__ wsO, const float* __restrict__ wsL,
    u16* __restrict__ attb)
{
    const int gi  = (blockIdx.x * 256 + threadIdx.x) * 8;
    const int row = gi >> 10;
    const int h   = (gi & 1023) >> 6;
    const float il = 1.0f / (wsL[h * 4096 + row] + wsL[(Hh + h) * 4096 + row]);
    const uint4 a = *(const uint4*)&wsO[gi];
    const uint4 c = *(const uint4*)&wsO[(size_t)4096 * 1024 + gi];
    const uint aw[4] = {a.x, a.y, a.z, a.w};
    const uint cw[4] = {c.x, c.y, c.z, c.w};
    uint ow[4];
    #pragma unroll
    for (int i = 0; i < 4; ++i) {
        const float r0 = (h2f((u16)(aw[i] & 0xffff)) + h2f((u16)(cw[i] & 0xffff))) * il;
        const float r1 = (h2f((u16)(aw[i] >> 16))    + h2f((u16)(cw[i] >> 16)))    * il;
        ow[i] = (uint)f2bf(r0) | ((uint)f2bf(r1) << 16);
    }
    uint4 o4; o4.x = ow[0]; o4.y = ow[1]; o4.z = ow[2]; o4.w = ow[3];
    *(uint4*)&attb[gi] = o4;
}

// ---------------------------------------------------------------------------
extern "C" void kernel_launch(void* const* d_in, const int* in_sizes, int n_in,
                              void* d_out, int out_size, void* d_ws, size_t ws_size,
                              hipStream_t stream) {
    const float* x    = (const float*)d_in[0];
    const float* Wqkv = (const float*)d_in[1];
    const float* bqkv = (const float*)d_in[2];
    const float* Wout = (const float*)d_in[3];
    const float* bout = (const float*)d_in[4];
    float* out = (float*)d_out;

    u16*   xb    = (u16*)d_ws;                               //  8 MB [4096][1024]
    u16*   WqT   = xb    + (size_t)4096 * 1024;              //  6 MB [3072][1024]
    u16*   WoT   = WqT   + (size_t)3072 * 1024;              //  2 MB [1024][1024]
    u16*   qkvb  = WoT   + (size_t)1024 * 1024;              // 16 MB [4096][2048] Q,K
    u16*   attb  = qkvb  + (size_t)4096 * 2048;              //  8 MB [4096][1024]
    u16*   vglob = attb  + (size_t)4096 * 1024;              //  8 MB [2][16][64][2048]
    u16*   wsO   = vglob + (size_t)4096 * 2048;              // 16 MB [2][4096][1024] fp16
    float* wsL   = (float*)(wsO + (size_t)2 * 4096 * 1024);  // 512 KB [2][16][4096]

    cvt_bf16<<<dim3((4096 * 1024) / 8 / 256), dim3(256), 0, stream>>>(x, xb);
    transpose_cvt<<<dim3(3072 / 64, 1024 / 64), dim3(256), 0, stream>>>(Wqkv, WqT, 1024, 3072);
    transpose_cvt<<<dim3(1024 / 64, 1024 / 64), dim3(256), 0, stream>>>(Wout, WoT, 1024, 1024);

    gemm_bt<1><<<dim3(3072 / 128, 4096 / 128), dim3(256), 0, stream>>>(
        xb, WqT, bqkv, qkvb, vglob, 4096, 3072, 1024);

    attn_split<<<dim3(Hh * Bb, 32), dim3(256), 0, stream>>>(qkvb, vglob, wsO, wsL);

    combine<<<dim3((4096 * 1024) / 8 / 256), dim3(256), 0, stream>>>(wsO, wsL, attb);

    gemm_bt<0><<<dim3(1024 / 128, 4096 / 128), dim3(256), 0, stream>>>(
        attb, WoT, bout, out, nullptr, 4096, 1024, 1024);
}